// Round 5
// baseline (21647.786 us; speedup 1.0000x reference)
//
#include <hip/hip_runtime.h>

// Problem constants
#define TSTEPS 300
// d_out float-element offsets: [outs 300*64*2 | r_m1 | r_pmd | r_s1]
#define OFF_RM1  38400
#define RSTRIDE  9830400    // 300*64*512 per rate region

// ws: fp32 x-state [3][64][512] (single buffer; each elem owned by one thread)
#define WS_X_FLOATS 98304

typedef float f4 __attribute__((ext_vector_type(4)));

// ---------------------------------------------------------------------------
// init: zero x-state, outs[0], rates[0] (tanh(0)=0). All fp32.
// ---------------------------------------------------------------------------
__global__ __launch_bounds__(256) void rnn_init(float* xstate, float* dout) {
  int gid = blockIdx.x * blockDim.x + threadIdx.x;
  int stride = gridDim.x * blockDim.x;
  for (int i = gid; i < WS_X_FLOATS; i += stride) xstate[i] = 0.f;
  for (int i = gid; i < 128; i += stride) dout[i] = 0.f;
  for (int i = gid; i < 3 * 32768; i += stride) {
    int rr = i >> 15, j = i & 32767;
    dout[OFF_RM1 + (size_t)rr * RSTRIDE + j] = 0.f;
  }
}

// ---------------------------------------------------------------------------
// one step t. grid = 97 blocks x 256.
// blk 0..31: m1 (16 cols each), 32..63: pmd, 64..95: s1, 96: lagged out-writer.
// thread = (nq = tid&3 -> 4 consecutive cols, bb = tid>>2 -> batch row).
// Weights read DIRECTLY from d_in ([k][n] row-major). Rates live fp32 in d_out.
// ---------------------------------------------------------------------------
__global__ __launch_bounds__(256) void rnn_step(
    const float* stim,
    const float* W_rec_m1, const float* W_rec_pmd, const float* W_rec_s1,
    const float* W_pmd_m1, const float* b_pmd_m1,
    const float* W_m1_pmd, const float* b_m1_pmd,
    const float* W_s1_pmd, const float* b_s1_pmd,
    const float* W_in_s1,  const float* b_in_s1,
    const float* W_out_m1, const float* b_out_m1,
    const float* W_fb_pmd, const float* b_fb_pmd,
    float* xstate, float* dout, int t)
{
  const int blk = blockIdx.x;
  const int tid = threadIdx.x;
  // rates at t-1, fp32, straight from d_out
  const float* rm1p  = dout + OFF_RM1 + (size_t)0 * RSTRIDE + (size_t)(t - 1) * 32768;
  const float* rpmdp = dout + OFF_RM1 + (size_t)1 * RSTRIDE + (size_t)(t - 1) * 32768;
  const float* rs1p  = dout + OFF_RM1 + (size_t)2 * RSTRIDE + (size_t)(t - 1) * 32768;

  if (blk == 96) {
    // outs[t-1] = r_m1[t-1] @ W_out + b_out  (outs[0] from init)
    if (t > 1 && tid < 128) {
      int b = tid >> 1, d = tid & 1;
      const float* rm = rm1p + b * 512;
      float o = 0.f;
      for (int k = 0; k < 512; ++k) o = fmaf(rm[k], W_out_m1[k * 2 + d], o);
      dout[(t - 1) * 128 + b * 2 + d] = o + b_out_m1[d];
    }
    return;
  }

  const int region = blk >> 5;          // 0=m1, 1=pmd, 2=s1
  const int n0 = (blk & 31) << 4;
  const int nq = tid & 3;
  const int bb = tid >> 2;
  const int n  = n0 + nq * 4;

  // ---- GEMM: pre[n..n+3] = sum over segments of (r_src[t-1] @ W_seg) ----
  f4 acc = {0.f, 0.f, 0.f, 0.f};
  const int NSEG = (region == 1) ? 3 : (region == 0) ? 2 : 1;
  for (int s = 0; s < NSEG; ++s) {
    const float* W;
    const float* ar;
    if (region == 0)      { W = s ? W_pmd_m1 : W_rec_m1;  ar = s ? rpmdp : rm1p; }
    else if (region == 1) { W = (s == 0) ? W_m1_pmd : (s == 1) ? W_rec_pmd : W_s1_pmd;
                            ar = (s == 0) ? rm1p : (s == 1) ? rpmdp : rs1p; }
    else                  { W = W_rec_s1; ar = rs1p; }
    ar += bb * 512;
    for (int k0 = 0; k0 < 512; k0 += 4) {
      f4 r = *(const f4*)(ar + k0);
      const float* wp = W + (size_t)k0 * 512 + n;
      f4 w0 = *(const f4*)(wp);
      f4 w1 = *(const f4*)(wp + 512);
      f4 w2 = *(const f4*)(wp + 1024);
      f4 w3 = *(const f4*)(wp + 1536);
      acc += r.x * w0;
      acc += r.y * w1;
      acc += r.z * w2;
      acc += r.w * w3;
    }
  }

  f4 pre = acc;
  if (region == 0) {
    pre += *(const f4*)(b_pmd_m1 + n);
  } else if (region == 1) {
    pre += *(const f4*)(b_m1_pmd + n);
    pre += *(const f4*)(b_s1_pmd + n);
    pre += *(const f4*)(b_fb_pmd + n);
    if (t > 1) {
      // recompute out_{t-1} for this batch row from r_m1[t-1] (fp32)
      const float* rm = rm1p + bb * 512;
      float o0 = 0.f, o1 = 0.f;
      for (int k0 = 0; k0 < 512; k0 += 4) {
        f4 r  = *(const f4*)(rm + k0);
        f4 wa = *(const f4*)(W_out_m1 + k0 * 2);
        f4 wb = *(const f4*)(W_out_m1 + k0 * 2 + 4);
        o0 += r.x * wa.x + r.y * wa.z + r.z * wb.x + r.w * wb.z;
        o1 += r.x * wa.y + r.y * wa.w + r.z * wb.y + r.w * wb.w;
      }
      o0 += b_out_m1[0];
      o1 += b_out_m1[1];
      f4 fb0 = *(const f4*)(W_fb_pmd + n);         // row d=0
      f4 fb1 = *(const f4*)(W_fb_pmd + 512 + n);   // row d=1
      pre += o0 * fb0;
      pre += o1 * fb1;
    }
  } else {
    pre += *(const f4*)(b_in_s1 + n);
    const float* u = stim + (size_t)t * 640 + bb * 10;
    for (int k = 0; k < 10; ++k) {
      f4 wi = *(const f4*)(W_in_s1 + k * 512 + n);
      pre += u[k] * wi;
    }
  }

  // ---- leaky update + tanh; x in-place (thread-owned), rate fp32 to d_out --
  const int xi = region * 32768 + bb * 512 + n;
  f4 xp = *(const f4*)(xstate + xi);
  f4 xn = 0.8f * xp + 0.2f * pre;
  *(f4*)(xstate + xi) = xn;
  f4 rv = {tanhf(xn.x), tanhf(xn.y), tanhf(xn.z), tanhf(xn.w)};
  float* rh = dout + OFF_RM1 + (size_t)region * RSTRIDE + (size_t)t * 32768 + bb * 512 + n;
  *(f4*)rh = rv;
}

// ---------------------------------------------------------------------------
// tail: outs[299] (the lagged writer covers 1..298)
// ---------------------------------------------------------------------------
__global__ __launch_bounds__(128) void rnn_out_tail(
    const float* W_out_m1, const float* b_out_m1, float* dout)
{
  int tid = threadIdx.x;
  if (tid >= 128) return;
  const float* rlast = dout + OFF_RM1 + (size_t)(TSTEPS - 1) * 32768;  // r_m1[299]
  int b = tid >> 1, d = tid & 1;
  const float* rm = rlast + b * 512;
  float o = 0.f;
  for (int k = 0; k < 512; ++k) o = fmaf(rm[k], W_out_m1[k * 2 + d], o);
  dout[(TSTEPS - 1) * 128 + b * 2 + d] = o + b_out_m1[d];
}

extern "C" void kernel_launch(void* const* d_in, const int* in_sizes, int n_in,
                              void* d_out, int out_size, void* d_ws, size_t ws_size,
                              hipStream_t stream) {
  const float* stim      = (const float*)d_in[0];
  const float* W_rec_m1  = (const float*)d_in[1];
  const float* W_rec_pmd = (const float*)d_in[2];
  const float* W_rec_s1  = (const float*)d_in[3];
  const float* W_pmd_m1  = (const float*)d_in[4];
  const float* b_pmd_m1  = (const float*)d_in[5];
  const float* W_m1_pmd  = (const float*)d_in[6];
  const float* b_m1_pmd  = (const float*)d_in[7];
  const float* W_s1_pmd  = (const float*)d_in[8];
  const float* b_s1_pmd  = (const float*)d_in[9];
  const float* W_in_s1   = (const float*)d_in[10];
  const float* b_in_s1   = (const float*)d_in[11];
  const float* W_out_m1  = (const float*)d_in[12];
  const float* b_out_m1  = (const float*)d_in[13];
  const float* W_fb_pmd  = (const float*)d_in[14];
  const float* b_fb_pmd  = (const float*)d_in[15];

  float* xstate = (float*)d_ws;
  float* dout   = (float*)d_out;

  hipLaunchKernelGGL(rnn_init, dim3(512), dim3(256), 0, stream, xstate, dout);

  for (int t = 1; t < TSTEPS; ++t) {
    hipLaunchKernelGGL(rnn_step, dim3(97), dim3(256), 0, stream,
                       stim,
                       W_rec_m1, W_rec_pmd, W_rec_s1,
                       W_pmd_m1, b_pmd_m1, W_m1_pmd, b_m1_pmd,
                       W_s1_pmd, b_s1_pmd, W_in_s1, b_in_s1,
                       W_out_m1, b_out_m1, W_fb_pmd, b_fb_pmd,
                       xstate, dout, t);
  }

  hipLaunchKernelGGL(rnn_out_tail, dim3(1), dim3(128), 0, stream,
                     W_out_m1, b_out_m1, dout);
}